// Round 2
// 212.784 us; speedup vs baseline: 1.0096x; 1.0096x over previous
//
#include <hip/hip_runtime.h>

// GAT layer: B=8, N=2048, Fin=Fout=64
// k01: blocks 0..255    = k1: Wh=h@W (MFMA) stored in MFMA-B-fragment order (whF) + s,t fp32
//      blocks 256..1279 = k0: pack adj!=0 into bitmask bytes (134 MB -> 4 MB), pure stream
// k2 : masked softmax + P@Wh. 32 rows/block (grid 512 = exactly 2 blocks/CU, no tail).
//      p = mask ? max(al*e^t, cl*e^{a t}) : 0  (max == the m>1 select, 1 VALU op)
//      z computed by a 5th "ones-column" MFMA B-fragment -> no shfl reduce, no zp.

#define ALPHA 0.2f

typedef __attribute__((ext_vector_type(8))) short  short8;
typedef __attribute__((ext_vector_type(4))) float  f32x4;

static __device__ __forceinline__ unsigned short f2bf(float f) {
    unsigned u = __builtin_bit_cast(unsigned, f);
    u += 0x7fffu + ((u >> 16) & 1u);   // round-to-nearest-even
    return (unsigned short)(u >> 16);
}

// two f32 -> packed bf16x2 (lo in low half), round-half-up
static __device__ __forceinline__ unsigned pack_bf2(float lo, float hi) {
    unsigned ulo = __builtin_bit_cast(unsigned, lo) + 0x8000u;
    unsigned uhi = __builtin_bit_cast(unsigned, hi) + 0x8000u;
    return __builtin_amdgcn_perm(uhi, ulo, 0x07060302);
}

// ---------------- k01 (unchanged) ----------------
__global__ __launch_bounds__(256) void k01(
    const float* __restrict__ h, const int* __restrict__ adj,
    const float* __restrict__ W, const float* __restrict__ a,
    uint4* __restrict__ whF, float* __restrict__ sw,
    float* __restrict__ tw, unsigned char* __restrict__ mask)
{
    __shared__ float W_l[64 * 65];
    __shared__ float wa[128];
    __shared__ float tile[4 * 16 * 65];

    const int tid = threadIdx.x;

    if (blockIdx.x >= 256) {
        // ---- k0: adj -> bitmask bytes; byte p covers j = p*8..p*8+7 ----
        const int mb = blockIdx.x - 256;          // 0..1023
        const int4* a4 = (const int4*)adj;
        #pragma unroll 1
        for (int g0 = 0; g0 < 16; g0 += 4) {
            int4 v0a, v0b, v1a, v1b, v2a, v2b, v3a, v3b;
            const size_t p0 = (size_t)mb * 4096 + (size_t)g0 * 256 + tid;
            v0a = a4[p0 * 2];          v0b = a4[p0 * 2 + 1];
            v1a = a4[(p0 + 256) * 2];  v1b = a4[(p0 + 256) * 2 + 1];
            v2a = a4[(p0 + 512) * 2];  v2b = a4[(p0 + 512) * 2 + 1];
            v3a = a4[(p0 + 768) * 2];  v3b = a4[(p0 + 768) * 2 + 1];
            unsigned b0 = (v0a.x ? 1u:0u)|(v0a.y ? 2u:0u)|(v0a.z ? 4u:0u)|(v0a.w ? 8u:0u)
                        | (v0b.x ?16u:0u)|(v0b.y ?32u:0u)|(v0b.z ?64u:0u)|(v0b.w ?128u:0u);
            unsigned b1 = (v1a.x ? 1u:0u)|(v1a.y ? 2u:0u)|(v1a.z ? 4u:0u)|(v1a.w ? 8u:0u)
                        | (v1b.x ?16u:0u)|(v1b.y ?32u:0u)|(v1b.z ?64u:0u)|(v1b.w ?128u:0u);
            unsigned b2 = (v2a.x ? 1u:0u)|(v2a.y ? 2u:0u)|(v2a.z ? 4u:0u)|(v2a.w ? 8u:0u)
                        | (v2b.x ?16u:0u)|(v2b.y ?32u:0u)|(v2b.z ?64u:0u)|(v2b.w ?128u:0u);
            unsigned b3 = (v3a.x ? 1u:0u)|(v3a.y ? 2u:0u)|(v3a.z ? 4u:0u)|(v3a.w ? 8u:0u)
                        | (v3b.x ?16u:0u)|(v3b.y ?32u:0u)|(v3b.z ?64u:0u)|(v3b.w ?128u:0u);
            mask[p0]       = (unsigned char)b0;
            mask[p0 + 256] = (unsigned char)b1;
            mask[p0 + 512] = (unsigned char)b2;
            mask[p0 + 768] = (unsigned char)b3;
        }
        return;
    }

    // ---- k1: Wh + s,t ----
    const int lane = tid & 63, wv = tid >> 6;
    const int im   = lane & 15, kq = lane >> 4;

    #pragma unroll
    for (int k = 0; k < 16; ++k) {
        int e = tid + 256 * k;
        W_l[(e >> 6) * 65 + (e & 63)] = W[e];
    }
    __syncthreads();

    if (tid < 128) {
        int f = tid & 63;
        const float* ap = a + (tid >> 6) * 64;
        float acc = 0.f;
        #pragma unroll 8
        for (int o = 0; o < 64; ++o) acc += W_l[f * 65 + o] * ap[o];
        wa[tid] = acc;
    }
    __syncthreads();

    short8 bf[4][2];
    #pragma unroll
    for (int nb = 0; nb < 4; ++nb)
        #pragma unroll
        for (int ks = 0; ks < 2; ++ks)
            #pragma unroll
            for (int u = 0; u < 8; ++u)
                bf[nb][ks][u] = (short)f2bf(W_l[(ks * 32 + kq * 8 + u) * 65 + nb * 16 + im]);

    const int row0 = blockIdx.x * 64 + wv * 16;
    const float* hrow = h + (size_t)(row0 + im) * 64;

    float hv[2][8];
    short8 af[2];
    float sp = 0.f, tp = 0.f;
    #pragma unroll
    for (int ks = 0; ks < 2; ++ks) {
        float4 A = *(const float4*)(hrow + ks * 32 + kq * 8);
        float4 Bv = *(const float4*)(hrow + ks * 32 + kq * 8 + 4);
        hv[ks][0] = A.x;  hv[ks][1] = A.y;  hv[ks][2] = A.z;  hv[ks][3] = A.w;
        hv[ks][4] = Bv.x; hv[ks][5] = Bv.y; hv[ks][6] = Bv.z; hv[ks][7] = Bv.w;
        #pragma unroll
        for (int u = 0; u < 8; ++u) {
            int f = ks * 32 + kq * 8 + u;
            sp += hv[ks][u] * wa[f];
            tp += hv[ks][u] * wa[64 + f];
            af[ks][u] = (short)f2bf(hv[ks][u]);
        }
    }
    sp += __shfl_xor(sp, 16, 64); sp += __shfl_xor(sp, 32, 64);
    tp += __shfl_xor(tp, 16, 64); tp += __shfl_xor(tp, 32, 64);
    if (lane < 16) {
        sw[row0 + lane] = sp;
        tw[row0 + lane] = tp;
    }

    f32x4 acc[4] = {{0.f,0.f,0.f,0.f},{0.f,0.f,0.f,0.f},{0.f,0.f,0.f,0.f},{0.f,0.f,0.f,0.f}};
    #pragma unroll
    for (int ks = 0; ks < 2; ++ks)
        #pragma unroll
        for (int nb = 0; nb < 4; ++nb)
            acc[nb] = __builtin_amdgcn_mfma_f32_16x16x32_bf16(af[ks], bf[nb][ks], acc[nb], 0, 0, 0);

    #pragma unroll
    for (int nb = 0; nb < 4; ++nb)
        #pragma unroll
        for (int r = 0; r < 4; ++r)
            tile[wv * 1040 + (kq * 4 + r) * 65 + nb * 16 + im] = acc[nb][r];
    __syncthreads();

    // ---- store Wh in MFMA-B-fragment order ----
    {
        const int blk_row0 = blockIdx.x * 64;
        const int bb2 = blk_row0 >> 11;
        const int c_base = (blk_row0 & 2047) >> 5;
        #pragma unroll
        for (int k = 0; k < 2; ++k) {
            int e = tid + 256 * k;
            int l = e & 63, ot = (e >> 6) & 3, cl_ = e >> 8;
            int o = ot * 16 + (l & 15);
            int jb = cl_ * 32 + (l >> 4) * 8;
            unsigned d0, d1, d2, d3;
            {
                int j0 = jb;
                d0 = pack_bf2(tile[(j0 >> 4) * 1040 + (j0 & 15) * 65 + o],
                              tile[(j0 >> 4) * 1040 + ((j0 & 15) + 1) * 65 + o]);
                j0 = jb + 2;
                d1 = pack_bf2(tile[(j0 >> 4) * 1040 + (j0 & 15) * 65 + o],
                              tile[(j0 >> 4) * 1040 + ((j0 & 15) + 1) * 65 + o]);
                j0 = jb + 4;
                d2 = pack_bf2(tile[(j0 >> 4) * 1040 + (j0 & 15) * 65 + o],
                              tile[(j0 >> 4) * 1040 + ((j0 & 15) + 1) * 65 + o]);
                j0 = jb + 6;
                d3 = pack_bf2(tile[(j0 >> 4) * 1040 + (j0 & 15) * 65 + o],
                              tile[(j0 >> 4) * 1040 + ((j0 & 15) + 1) * 65 + o]);
            }
            uint4 val = {d0, d1, d2, d3};
            whF[(size_t)(((bb2 * 64 + c_base + cl_) * 4 + ot)) * 64 + l] = val;
        }
    }
}

// ---------------- k2: masked softmax + P@Wh ----------------
// grid 512 (b, i0: 32 rows) x 256 thr; wave = 512-j stripe, 2 row-tiles of 16.
__global__ __launch_bounds__(256, 2) void k2_attn(
    const unsigned* __restrict__ mask, const uint4* __restrict__ whF,
    const float* __restrict__ sw, const float* __restrict__ tw,
    float* __restrict__ out)
{
    __shared__ float eB[2048];
    __shared__ float eD[2048];
    __shared__ float cpart[4 * 2176];   // [wv][row 0..31][col 0..67]; col 64 = z

    const int tid  = threadIdx.x;
    const int lane = tid & 63, wv = tid >> 6;
    const int im   = lane & 15, kq = lane >> 4;
    const int b    = blockIdx.x >> 6;
    const int i0   = (blockIdx.x & 63) << 5;

    // exp tables: eB[j]=exp(t_j), eD[j]=exp(ALPHA*t_j)
    {
        const float4* tp4 = (const float4*)(tw + (size_t)b * 2048);
        float4 t0 = tp4[tid], t1 = tp4[tid + 256];
        float4 e0 = {__expf(t0.x), __expf(t0.y), __expf(t0.z), __expf(t0.w)};
        float4 e1 = {__expf(t1.x), __expf(t1.y), __expf(t1.z), __expf(t1.w)};
        float4 f0 = {__expf(ALPHA*t0.x), __expf(ALPHA*t0.y), __expf(ALPHA*t0.z), __expf(ALPHA*t0.w)};
        float4 f1 = {__expf(ALPHA*t1.x), __expf(ALPHA*t1.y), __expf(ALPHA*t1.z), __expf(ALPHA*t1.w)};
        *(float4*)&eB[tid * 4] = e0;  *(float4*)&eB[(tid + 256) * 4] = e1;
        *(float4*)&eD[tid * 4] = f0;  *(float4*)&eD[(tid + 256) * 4] = f1;
    }

    // mask preload: rows i0+im (tile0) and i0+16+im (tile1), j in [wv*512, wv*512+512)
    const uint4* mr0 = (const uint4*)(mask + (size_t)(b * 2048 + i0 + im) * 64 + wv * 16);
    const uint4* mr1 = (const uint4*)(mask + (size_t)(b * 2048 + i0 + 16 + im) * 64 + wv * 16);
    const uint4 mA0 = mr0[0], mB0 = mr0[1], mC0 = mr0[2], mD0 = mr0[3];
    const uint4 mA1 = mr1[0], mB1 = mr1[1], mC1 = mr1[2], mD1 = mr1[3];
    const unsigned mm0[16] = {mA0.x, mA0.y, mA0.z, mA0.w, mB0.x, mB0.y, mB0.z, mB0.w,
                              mC0.x, mC0.y, mC0.z, mC0.w, mD0.x, mD0.y, mD0.z, mD0.w};
    const unsigned mm1[16] = {mA1.x, mA1.y, mA1.z, mA1.w, mB1.x, mB1.y, mB1.z, mB1.w,
                              mC1.x, mC1.y, mC1.z, mC1.w, mD1.x, mD1.y, mD1.z, mD1.w};

    const float sl0 = sw[b * 2048 + i0 + im];
    const float sl1 = sw[b * 2048 + i0 + 16 + im];
    const float al0 = __expf(sl0), cl0 = __expf(ALPHA * sl0);
    const float al1 = __expf(sl1), cl1 = __expf(ALPHA * sl1);

    const int j00 = wv * 512 + kq * 8;
    const uint4* wbase = whF + (size_t)((b * 64 + wv * 16) * 4) * 64 + lane;

    // ones-column B-fragment: B[k][0] = 1, else 0  ->  D[i][0] = row sum
    short8 onesf;
    {
        const short ov = (im == 0) ? (short)0x3F80 : (short)0;
        #pragma unroll
        for (int u = 0; u < 8; ++u) onesf[u] = ov;
    }

    __syncthreads();

    f32x4 acc0 = {0.f,0.f,0.f,0.f}, acc1 = {0.f,0.f,0.f,0.f};
    f32x4 acc2 = {0.f,0.f,0.f,0.f}, acc3 = {0.f,0.f,0.f,0.f};
    f32x4 acc4 = {0.f,0.f,0.f,0.f}, acc5 = {0.f,0.f,0.f,0.f};
    f32x4 acc6 = {0.f,0.f,0.f,0.f}, acc7 = {0.f,0.f,0.f,0.f};
    f32x4 az0  = {0.f,0.f,0.f,0.f}, az1  = {0.f,0.f,0.f,0.f};

    #pragma unroll
    for (int s = 0; s < 16; ++s) {
        const uint4 w0 = wbase[(s * 4 + 0) * 64];
        const uint4 w1 = wbase[(s * 4 + 1) * 64];
        const uint4 w2 = wbase[(s * 4 + 2) * 64];
        const uint4 w3 = wbase[(s * 4 + 3) * 64];

        const float4 bA  = *(const float4*)&eB[j00 + s * 32];
        const float4 bBv = *(const float4*)&eB[j00 + s * 32 + 4];
        const float4 dA  = *(const float4*)&eD[j00 + s * 32];
        const float4 dBv = *(const float4*)&eD[j00 + s * 32 + 4];
        const unsigned mb0 = (mm0[s] >> (kq * 8)) & 0xffu;
        const unsigned mb1 = (mm1[s] >> (kq * 8)) & 0xffu;

        // tile 0 (rows i0..i0+15):  p = mask ? max(al*e^t, cl*e^{a t}) : 0
        float p0 = fmaxf(al0 * bA.x,  cl0 * dA.x);   p0 = (mb0 &   1u) ? p0 : 0.f;
        float p1 = fmaxf(al0 * bA.y,  cl0 * dA.y);   p1 = (mb0 &   2u) ? p1 : 0.f;
        float p2 = fmaxf(al0 * bA.z,  cl0 * dA.z);   p2 = (mb0 &   4u) ? p2 : 0.f;
        float p3 = fmaxf(al0 * bA.w,  cl0 * dA.w);   p3 = (mb0 &   8u) ? p3 : 0.f;
        float p4 = fmaxf(al0 * bBv.x, cl0 * dBv.x);  p4 = (mb0 &  16u) ? p4 : 0.f;
        float p5 = fmaxf(al0 * bBv.y, cl0 * dBv.y);  p5 = (mb0 &  32u) ? p5 : 0.f;
        float p6 = fmaxf(al0 * bBv.z, cl0 * dBv.z);  p6 = (mb0 &  64u) ? p6 : 0.f;
        float p7 = fmaxf(al0 * bBv.w, cl0 * dBv.w);  p7 = (mb0 & 128u) ? p7 : 0.f;

        int4 ai0;
        ai0.x = (int)pack_bf2(p0, p1);
        ai0.y = (int)pack_bf2(p2, p3);
        ai0.z = (int)pack_bf2(p4, p5);
        ai0.w = (int)pack_bf2(p6, p7);
        const short8 af0 = __builtin_bit_cast(short8, ai0);

        // tile 1 (rows i0+16..i0+31)
        float q0 = fmaxf(al1 * bA.x,  cl1 * dA.x);   q0 = (mb1 &   1u) ? q0 : 0.f;
        float q1 = fmaxf(al1 * bA.y,  cl1 * dA.y);   q1 = (mb1 &   2u) ? q1 : 0.f;
        float q2 = fmaxf(al1 * bA.z,  cl1 * dA.z);   q2 = (mb1 &   4u) ? q2 : 0.f;
        float q3 = fmaxf(al1 * bA.w,  cl1 * dA.w);   q3 = (mb1 &   8u) ? q3 : 0.f;
        float q4 = fmaxf(al1 * bBv.x, cl1 * dBv.x);  q4 = (mb1 &  16u) ? q4 : 0.f;
        float q5 = fmaxf(al1 * bBv.y, cl1 * dBv.y);  q5 = (mb1 &  32u) ? q5 : 0.f;
        float q6 = fmaxf(al1 * bBv.z, cl1 * dBv.z);  q6 = (mb1 &  64u) ? q6 : 0.f;
        float q7 = fmaxf(al1 * bBv.w, cl1 * dBv.w);  q7 = (mb1 & 128u) ? q7 : 0.f;

        int4 ai1;
        ai1.x = (int)pack_bf2(q0, q1);
        ai1.y = (int)pack_bf2(q2, q3);
        ai1.z = (int)pack_bf2(q4, q5);
        ai1.w = (int)pack_bf2(q6, q7);
        const short8 af1 = __builtin_bit_cast(short8, ai1);

        acc0 = __builtin_amdgcn_mfma_f32_16x16x32_bf16(af0, __builtin_bit_cast(short8, w0), acc0, 0, 0, 0);
        acc1 = __builtin_amdgcn_mfma_f32_16x16x32_bf16(af0, __builtin_bit_cast(short8, w1), acc1, 0, 0, 0);
        acc2 = __builtin_amdgcn_mfma_f32_16x16x32_bf16(af0, __builtin_bit_cast(short8, w2), acc2, 0, 0, 0);
        acc3 = __builtin_amdgcn_mfma_f32_16x16x32_bf16(af0, __builtin_bit_cast(short8, w3), acc3, 0, 0, 0);
        az0  = __builtin_amdgcn_mfma_f32_16x16x32_bf16(af0, onesf, az0, 0, 0, 0);

        acc4 = __builtin_amdgcn_mfma_f32_16x16x32_bf16(af1, __builtin_bit_cast(short8, w0), acc4, 0, 0, 0);
        acc5 = __builtin_amdgcn_mfma_f32_16x16x32_bf16(af1, __builtin_bit_cast(short8, w1), acc5, 0, 0, 0);
        acc6 = __builtin_amdgcn_mfma_f32_16x16x32_bf16(af1, __builtin_bit_cast(short8, w2), acc6, 0, 0, 0);
        acc7 = __builtin_amdgcn_mfma_f32_16x16x32_bf16(af1, __builtin_bit_cast(short8, w3), acc7, 0, 0, 0);
        az1  = __builtin_amdgcn_mfma_f32_16x16x32_bf16(af1, onesf, az1, 0, 0, 0);
    }

    #pragma unroll
    for (int r = 0; r < 4; ++r) {
        const int row = kq * 4 + r;
        float* cp0 = &cpart[wv * 2176 + row * 68];
        cp0[ 0 + im] = acc0[r];
        cp0[16 + im] = acc1[r];
        cp0[32 + im] = acc2[r];
        cp0[48 + im] = acc3[r];
        float* cp1 = &cpart[wv * 2176 + (16 + row) * 68];
        cp1[ 0 + im] = acc4[r];
        cp1[16 + im] = acc5[r];
        cp1[32 + im] = acc6[r];
        cp1[48 + im] = acc7[r];
        if (im == 0) { cp0[64] = az0[r]; cp1[64] = az1[r]; }
    }
    __syncthreads();

    // epilogue: 2 float4 outputs per thread
    #pragma unroll
    for (int k = 0; k < 2; ++k) {
        const int idx4 = tid + 256 * k;        // 0..511
        const int i  = idx4 >> 4;              // 0..31
        const int oc = (idx4 & 15) << 2;       // 0,4,..,60
        const float4 s0 = *(const float4*)&cpart[0 * 2176 + i * 68 + oc];
        const float4 s1 = *(const float4*)&cpart[1 * 2176 + i * 68 + oc];
        const float4 s2 = *(const float4*)&cpart[2 * 2176 + i * 68 + oc];
        const float4 s3 = *(const float4*)&cpart[3 * 2176 + i * 68 + oc];
        float z = cpart[0 * 2176 + i * 68 + 64] + cpart[1 * 2176 + i * 68 + 64]
                + cpart[2 * 2176 + i * 68 + 64] + cpart[3 * 2176 + i * 68 + 64];
        if (z == 0.f) z = 1.f;
        const float inv = 1.f / z;
        float4 rv;
        rv.x = ((s0.x + s1.x) + (s2.x + s3.x)) * inv;
        rv.y = ((s0.y + s1.y) + (s2.y + s3.y)) * inv;
        rv.z = ((s0.z + s1.z) + (s2.z + s3.z)) * inv;
        rv.w = ((s0.w + s1.w) + (s2.w + s3.w)) * inv;
        rv.x = rv.x > 0.f ? rv.x : expm1f(rv.x);
        rv.y = rv.y > 0.f ? rv.y : expm1f(rv.y);
        rv.z = rv.z > 0.f ? rv.z : expm1f(rv.z);
        rv.w = rv.w > 0.f ? rv.w : expm1f(rv.w);
        *(float4*)(out + ((size_t)(b * 2048 + i0 + i)) * 64 + oc) = rv;
    }
}

extern "C" void kernel_launch(void* const* d_in, const int* in_sizes, int n_in,
                              void* d_out, int out_size, void* d_ws, size_t ws_size,
                              hipStream_t stream) {
    const float* h   = (const float*)d_in[0];
    const int*   adj = (const int*)d_in[1];
    const float* W   = (const float*)d_in[2];
    const float* a   = (const float*)d_in[3];
    float* out = (float*)d_out;

    uint4* whF = (uint4*)d_ws;                                           // 2 MiB
    float* sw  = (float*)((char*)d_ws + 2097152);                        // 64 KiB
    float* tw  = (float*)((char*)d_ws + 2097152 + 65536);                // 64 KiB
    unsigned char* mask = (unsigned char*)((char*)d_ws + 2097152 + 131072); // 4 MiB

    hipLaunchKernelGGL(k01, dim3(1280), dim3(256), 0, stream, h, adj, W, a, whF, sw, tw, mask);
    hipLaunchKernelGGL(k2_attn, dim3(512), dim3(256), 0, stream,
                       (const unsigned*)mask, whF, sw, tw, out);
}

// Round 4
// 204.536 us; speedup vs baseline: 1.0503x; 1.0403x over previous
//
#include <hip/hip_runtime.h>

// GAT layer: B=8, N=2048, Fin=Fout=64
// k1 : Wh=h@W (MFMA) stored in MFMA-B-fragment order (whF) + s,t fp32. grid 256.
// k2 : masked softmax + P@Wh, adj loaded DIRECTLY in the s-loop (no bitmask pass).
//      32 rows/block (grid 512 = 2 blocks/CU). p = adj ? max(al*e^t, cl*e^{a t}) : 0.
//      z via a 5th "ones-column" MFMA B-fragment. k2 is a single 134-MB adj stream;
//      all softmax/MFMA work hides under the HBM read.

#define ALPHA 0.2f

typedef __attribute__((ext_vector_type(8))) short  short8;
typedef __attribute__((ext_vector_type(4))) float  f32x4;

static __device__ __forceinline__ unsigned short f2bf(float f) {
    unsigned u = __builtin_bit_cast(unsigned, f);
    u += 0x7fffu + ((u >> 16) & 1u);   // round-to-nearest-even
    return (unsigned short)(u >> 16);
}

// two f32 -> packed bf16x2 (lo in low half), round-half-up
static __device__ __forceinline__ unsigned pack_bf2(float lo, float hi) {
    unsigned ulo = __builtin_bit_cast(unsigned, lo) + 0x8000u;
    unsigned uhi = __builtin_bit_cast(unsigned, hi) + 0x8000u;
    return __builtin_amdgcn_perm(uhi, ulo, 0x07060302);
}

// ---------------- k1: Wh + s,t ----------------
__global__ __launch_bounds__(256) void k1(
    const float* __restrict__ h, const float* __restrict__ W,
    const float* __restrict__ a, uint4* __restrict__ whF,
    float* __restrict__ sw, float* __restrict__ tw)
{
    __shared__ float W_l[64 * 65];
    __shared__ float wa[128];
    __shared__ float tile[4 * 16 * 65];

    const int tid = threadIdx.x;
    const int lane = tid & 63, wv = tid >> 6;
    const int im   = lane & 15, kq = lane >> 4;

    #pragma unroll
    for (int k = 0; k < 16; ++k) {
        int e = tid + 256 * k;
        W_l[(e >> 6) * 65 + (e & 63)] = W[e];
    }
    __syncthreads();

    if (tid < 128) {
        int f = tid & 63;
        const float* ap = a + (tid >> 6) * 64;
        float acc = 0.f;
        #pragma unroll 8
        for (int o = 0; o < 64; ++o) acc += W_l[f * 65 + o] * ap[o];
        wa[tid] = acc;
    }
    __syncthreads();

    short8 bf[4][2];
    #pragma unroll
    for (int nb = 0; nb < 4; ++nb)
        #pragma unroll
        for (int ks = 0; ks < 2; ++ks)
            #pragma unroll
            for (int u = 0; u < 8; ++u)
                bf[nb][ks][u] = (short)f2bf(W_l[(ks * 32 + kq * 8 + u) * 65 + nb * 16 + im]);

    const int row0 = blockIdx.x * 64 + wv * 16;
    const float* hrow = h + (size_t)(row0 + im) * 64;

    float hv[2][8];
    short8 af[2];
    float sp = 0.f, tp = 0.f;
    #pragma unroll
    for (int ks = 0; ks < 2; ++ks) {
        float4 A = *(const float4*)(hrow + ks * 32 + kq * 8);
        float4 Bv = *(const float4*)(hrow + ks * 32 + kq * 8 + 4);
        hv[ks][0] = A.x;  hv[ks][1] = A.y;  hv[ks][2] = A.z;  hv[ks][3] = A.w;
        hv[ks][4] = Bv.x; hv[ks][5] = Bv.y; hv[ks][6] = Bv.z; hv[ks][7] = Bv.w;
        #pragma unroll
        for (int u = 0; u < 8; ++u) {
            int f = ks * 32 + kq * 8 + u;
            sp += hv[ks][u] * wa[f];
            tp += hv[ks][u] * wa[64 + f];
            af[ks][u] = (short)f2bf(hv[ks][u]);
        }
    }
    sp += __shfl_xor(sp, 16, 64); sp += __shfl_xor(sp, 32, 64);
    tp += __shfl_xor(tp, 16, 64); tp += __shfl_xor(tp, 32, 64);
    if (lane < 16) {
        sw[row0 + lane] = sp;
        tw[row0 + lane] = tp;
    }

    f32x4 acc[4] = {{0.f,0.f,0.f,0.f},{0.f,0.f,0.f,0.f},{0.f,0.f,0.f,0.f},{0.f,0.f,0.f,0.f}};
    #pragma unroll
    for (int ks = 0; ks < 2; ++ks)
        #pragma unroll
        for (int nb = 0; nb < 4; ++nb)
            acc[nb] = __builtin_amdgcn_mfma_f32_16x16x32_bf16(af[ks], bf[nb][ks], acc[nb], 0, 0, 0);

    #pragma unroll
    for (int nb = 0; nb < 4; ++nb)
        #pragma unroll
        for (int r = 0; r < 4; ++r)
            tile[wv * 1040 + (kq * 4 + r) * 65 + nb * 16 + im] = acc[nb][r];
    __syncthreads();

    // ---- store Wh in MFMA-B-fragment order ----
    {
        const int blk_row0 = blockIdx.x * 64;
        const int bb2 = blk_row0 >> 11;
        const int c_base = (blk_row0 & 2047) >> 5;
        #pragma unroll
        for (int k = 0; k < 2; ++k) {
            int e = tid + 256 * k;
            int l = e & 63, ot = (e >> 6) & 3, cl_ = e >> 8;
            int o = ot * 16 + (l & 15);
            int jb = cl_ * 32 + (l >> 4) * 8;
            unsigned d0, d1, d2, d3;
            {
                int j0 = jb;
                d0 = pack_bf2(tile[(j0 >> 4) * 1040 + (j0 & 15) * 65 + o],
                              tile[(j0 >> 4) * 1040 + ((j0 & 15) + 1) * 65 + o]);
                j0 = jb + 2;
                d1 = pack_bf2(tile[(j0 >> 4) * 1040 + (j0 & 15) * 65 + o],
                              tile[(j0 >> 4) * 1040 + ((j0 & 15) + 1) * 65 + o]);
                j0 = jb + 4;
                d2 = pack_bf2(tile[(j0 >> 4) * 1040 + (j0 & 15) * 65 + o],
                              tile[(j0 >> 4) * 1040 + ((j0 & 15) + 1) * 65 + o]);
                j0 = jb + 6;
                d3 = pack_bf2(tile[(j0 >> 4) * 1040 + (j0 & 15) * 65 + o],
                              tile[(j0 >> 4) * 1040 + ((j0 & 15) + 1) * 65 + o]);
            }
            uint4 val = {d0, d1, d2, d3};
            whF[(size_t)(((bb2 * 64 + c_base + cl_) * 4 + ot)) * 64 + l] = val;
        }
    }
}

// ---------------- k2: masked softmax + P@Wh ----------------
// grid 512 (b, i0: 32 rows) x 256 thr; wave = 512-j stripe, 2 row-tiles of 16.
// adj is read directly: per iter s, lane (im,kq) loads 2x int4 per row; the 4 kq
// lanes x 2 loads tile a contiguous 128-B line per row -> HBM-efficient stream.
__global__ __launch_bounds__(256, 2) void k2_attn(
    const int* __restrict__ adj, const uint4* __restrict__ whF,
    const float* __restrict__ sw, const float* __restrict__ tw,
    float* __restrict__ out)
{
    __shared__ float eB[2048];
    __shared__ float eD[2048];
    __shared__ float cpart[4 * 2176];   // [wv][row 0..31][col 0..67]; col 64 = z

    const int tid  = threadIdx.x;
    const int lane = tid & 63, wv = tid >> 6;
    const int im   = lane & 15, kq = lane >> 4;
    const int b    = blockIdx.x >> 6;
    const int i0   = (blockIdx.x & 63) << 5;

    // exp tables: eB[j]=exp(t_j), eD[j]=exp(ALPHA*t_j)
    {
        const float4* tp4 = (const float4*)(tw + (size_t)b * 2048);
        float4 t0 = tp4[tid], t1 = tp4[tid + 256];
        float4 e0 = {__expf(t0.x), __expf(t0.y), __expf(t0.z), __expf(t0.w)};
        float4 e1 = {__expf(t1.x), __expf(t1.y), __expf(t1.z), __expf(t1.w)};
        float4 f0 = {__expf(ALPHA*t0.x), __expf(ALPHA*t0.y), __expf(ALPHA*t0.z), __expf(ALPHA*t0.w)};
        float4 f1 = {__expf(ALPHA*t1.x), __expf(ALPHA*t1.y), __expf(ALPHA*t1.z), __expf(ALPHA*t1.w)};
        *(float4*)&eB[tid * 4] = e0;  *(float4*)&eB[(tid + 256) * 4] = e1;
        *(float4*)&eD[tid * 4] = f0;  *(float4*)&eD[(tid + 256) * 4] = f1;
    }

    const int j00 = wv * 512 + kq * 8;
    // adj row pointers (int4 granularity). iter s uses indices s*8 and s*8+1.
    const int4* arow0 = (const int4*)(adj + (size_t)(b * 2048 + i0 + im) * 2048) + (j00 >> 2);
    const int4* arow1 = (const int4*)(adj + (size_t)(b * 2048 + i0 + 16 + im) * 2048) + (j00 >> 2);

    const float sl0 = sw[b * 2048 + i0 + im];
    const float sl1 = sw[b * 2048 + i0 + 16 + im];
    const float al0 = __expf(sl0), cl0 = __expf(ALPHA * sl0);
    const float al1 = __expf(sl1), cl1 = __expf(ALPHA * sl1);

    const uint4* wbase = whF + (size_t)((b * 64 + wv * 16) * 4) * 64 + lane;

    // ones-column B-fragment: B[k][0] = 1, else 0  ->  D[i][0] = row sum
    short8 onesf;
    {
        const short ov = (im == 0) ? (short)0x3F80 : (short)0;
        #pragma unroll
        for (int u = 0; u < 8; ++u) onesf[u] = ov;
    }

    __syncthreads();

    f32x4 acc0 = {0.f,0.f,0.f,0.f}, acc1 = {0.f,0.f,0.f,0.f};
    f32x4 acc2 = {0.f,0.f,0.f,0.f}, acc3 = {0.f,0.f,0.f,0.f};
    f32x4 acc4 = {0.f,0.f,0.f,0.f}, acc5 = {0.f,0.f,0.f,0.f};
    f32x4 acc6 = {0.f,0.f,0.f,0.f}, acc7 = {0.f,0.f,0.f,0.f};
    f32x4 az0  = {0.f,0.f,0.f,0.f}, az1  = {0.f,0.f,0.f,0.f};

    #pragma unroll
    for (int s = 0; s < 16; ++s) {
        const uint4 w0 = wbase[(s * 4 + 0) * 64];
        const uint4 w1 = wbase[(s * 4 + 1) * 64];
        const uint4 w2 = wbase[(s * 4 + 2) * 64];
        const uint4 w3 = wbase[(s * 4 + 3) * 64];

        const int4 a0A = arow0[s * 8];
        const int4 a0B = arow0[s * 8 + 1];
        const int4 a1A = arow1[s * 8];
        const int4 a1B = arow1[s * 8 + 1];

        const float4 bA  = *(const float4*)&eB[j00 + s * 32];
        const float4 bBv = *(const float4*)&eB[j00 + s * 32 + 4];
        const float4 dA  = *(const float4*)&eD[j00 + s * 32];
        const float4 dBv = *(const float4*)&eD[j00 + s * 32 + 4];

        // tile 0 (rows i0..i0+15):  p = adj ? max(al*e^t, cl*e^{a t}) : 0
        float p0 = fmaxf(al0 * bA.x,  cl0 * dA.x);   p0 = a0A.x ? p0 : 0.f;
        float p1 = fmaxf(al0 * bA.y,  cl0 * dA.y);   p1 = a0A.y ? p1 : 0.f;
        float p2 = fmaxf(al0 * bA.z,  cl0 * dA.z);   p2 = a0A.z ? p2 : 0.f;
        float p3 = fmaxf(al0 * bA.w,  cl0 * dA.w);   p3 = a0A.w ? p3 : 0.f;
        float p4 = fmaxf(al0 * bBv.x, cl0 * dBv.x);  p4 = a0B.x ? p4 : 0.f;
        float p5 = fmaxf(al0 * bBv.y, cl0 * dBv.y);  p5 = a0B.y ? p5 : 0.f;
        float p6 = fmaxf(al0 * bBv.z, cl0 * dBv.z);  p6 = a0B.z ? p6 : 0.f;
        float p7 = fmaxf(al0 * bBv.w, cl0 * dBv.w);  p7 = a0B.w ? p7 : 0.f;

        int4 ai0;
        ai0.x = (int)pack_bf2(p0, p1);
        ai0.y = (int)pack_bf2(p2, p3);
        ai0.z = (int)pack_bf2(p4, p5);
        ai0.w = (int)pack_bf2(p6, p7);
        const short8 af0 = __builtin_bit_cast(short8, ai0);

        // tile 1 (rows i0+16..i0+31)
        float q0 = fmaxf(al1 * bA.x,  cl1 * dA.x);   q0 = a1A.x ? q0 : 0.f;
        float q1 = fmaxf(al1 * bA.y,  cl1 * dA.y);   q1 = a1A.y ? q1 : 0.f;
        float q2 = fmaxf(al1 * bA.z,  cl1 * dA.z);   q2 = a1A.z ? q2 : 0.f;
        float q3 = fmaxf(al1 * bA.w,  cl1 * dA.w);   q3 = a1A.w ? q3 : 0.f;
        float q4 = fmaxf(al1 * bBv.x, cl1 * dBv.x);  q4 = a1B.x ? q4 : 0.f;
        float q5 = fmaxf(al1 * bBv.y, cl1 * dBv.y);  q5 = a1B.y ? q5 : 0.f;
        float q6 = fmaxf(al1 * bBv.z, cl1 * dBv.z);  q6 = a1B.z ? q6 : 0.f;
        float q7 = fmaxf(al1 * bBv.w, cl1 * dBv.w);  q7 = a1B.w ? q7 : 0.f;

        int4 ai1;
        ai1.x = (int)pack_bf2(q0, q1);
        ai1.y = (int)pack_bf2(q2, q3);
        ai1.z = (int)pack_bf2(q4, q5);
        ai1.w = (int)pack_bf2(q6, q7);
        const short8 af1 = __builtin_bit_cast(short8, ai1);

        acc0 = __builtin_amdgcn_mfma_f32_16x16x32_bf16(af0, __builtin_bit_cast(short8, w0), acc0, 0, 0, 0);
        acc1 = __builtin_amdgcn_mfma_f32_16x16x32_bf16(af0, __builtin_bit_cast(short8, w1), acc1, 0, 0, 0);
        acc2 = __builtin_amdgcn_mfma_f32_16x16x32_bf16(af0, __builtin_bit_cast(short8, w2), acc2, 0, 0, 0);
        acc3 = __builtin_amdgcn_mfma_f32_16x16x32_bf16(af0, __builtin_bit_cast(short8, w3), acc3, 0, 0, 0);
        az0  = __builtin_amdgcn_mfma_f32_16x16x32_bf16(af0, onesf, az0, 0, 0, 0);

        acc4 = __builtin_amdgcn_mfma_f32_16x16x32_bf16(af1, __builtin_bit_cast(short8, w0), acc4, 0, 0, 0);
        acc5 = __builtin_amdgcn_mfma_f32_16x16x32_bf16(af1, __builtin_bit_cast(short8, w1), acc5, 0, 0, 0);
        acc6 = __builtin_amdgcn_mfma_f32_16x16x32_bf16(af1, __builtin_bit_cast(short8, w2), acc6, 0, 0, 0);
        acc7 = __builtin_amdgcn_mfma_f32_16x16x32_bf16(af1, __builtin_bit_cast(short8, w3), acc7, 0, 0, 0);
        az1  = __builtin_amdgcn_mfma_f32_16x16x32_bf16(af1, onesf, az1, 0, 0, 0);
    }

    #pragma unroll
    for (int r = 0; r < 4; ++r) {
        const int row = kq * 4 + r;
        float* cp0 = &cpart[wv * 2176 + row * 68];
        cp0[ 0 + im] = acc0[r];
        cp0[16 + im] = acc1[r];
        cp0[32 + im] = acc2[r];
        cp0[48 + im] = acc3[r];
        float* cp1 = &cpart[wv * 2176 + (16 + row) * 68];
        cp1[ 0 + im] = acc4[r];
        cp1[16 + im] = acc5[r];
        cp1[32 + im] = acc6[r];
        cp1[48 + im] = acc7[r];
        if (im == 0) { cp0[64] = az0[r]; cp1[64] = az1[r]; }
    }
    __syncthreads();

    // epilogue: 2 float4 outputs per thread
    #pragma unroll
    for (int k = 0; k < 2; ++k) {
        const int idx4 = tid + 256 * k;        // 0..511
        const int i  = idx4 >> 4;              // 0..31
        const int oc = (idx4 & 15) << 2;       // 0,4,..,60
        const float4 s0 = *(const float4*)&cpart[0 * 2176 + i * 68 + oc];
        const float4 s1 = *(const float4*)&cpart[1 * 2176 + i * 68 + oc];
        const float4 s2 = *(const float4*)&cpart[2 * 2176 + i * 68 + oc];
        const float4 s3 = *(const float4*)&cpart[3 * 2176 + i * 68 + oc];
        float z = cpart[0 * 2176 + i * 68 + 64] + cpart[1 * 2176 + i * 68 + 64]
                + cpart[2 * 2176 + i * 68 + 64] + cpart[3 * 2176 + i * 68 + 64];
        if (z == 0.f) z = 1.f;
        const float inv = 1.f / z;
        float4 rv;
        rv.x = ((s0.x + s1.x) + (s2.x + s3.x)) * inv;
        rv.y = ((s0.y + s1.y) + (s2.y + s3.y)) * inv;
        rv.z = ((s0.z + s1.z) + (s2.z + s3.z)) * inv;
        rv.w = ((s0.w + s1.w) + (s2.w + s3.w)) * inv;
        rv.x = rv.x > 0.f ? rv.x : expm1f(rv.x);
        rv.y = rv.y > 0.f ? rv.y : expm1f(rv.y);
        rv.z = rv.z > 0.f ? rv.z : expm1f(rv.z);
        rv.w = rv.w > 0.f ? rv.w : expm1f(rv.w);
        *(float4*)(out + ((size_t)(b * 2048 + i0 + i)) * 64 + oc) = rv;
    }
}

extern "C" void kernel_launch(void* const* d_in, const int* in_sizes, int n_in,
                              void* d_out, int out_size, void* d_ws, size_t ws_size,
                              hipStream_t stream) {
    const float* h   = (const float*)d_in[0];
    const int*   adj = (const int*)d_in[1];
    const float* W   = (const float*)d_in[2];
    const float* a   = (const float*)d_in[3];
    float* out = (float*)d_out;

    uint4* whF = (uint4*)d_ws;                                           // 2 MiB
    float* sw  = (float*)((char*)d_ws + 2097152);                        // 64 KiB
    float* tw  = (float*)((char*)d_ws + 2097152 + 65536);                // 64 KiB

    hipLaunchKernelGGL(k1, dim3(256), dim3(256), 0, stream, h, W, a, whF, sw, tw);
    hipLaunchKernelGGL(k2_attn, dim3(512), dim3(256), 0, stream,
                       adj, whF, sw, tw, out);
}